// Round 7
// baseline (264.407 us; speedup 1.0000x reference)
//
#include <hip/hip_runtime.h>
#include <hip/hip_bf16.h>

// Problem constants: B=2, H=W=64, T=4096, C=192
#define BATCH 2
#define TLEN 4096
#define CC 192
#define PADC 2

typedef __attribute__((ext_vector_type(8))) short bf16x8;
typedef __attribute__((ext_vector_type(4))) float f32x4;

__device__ __constant__ float PRF_X[16] = {-2,-2,-2,-2, -2,-1,0,1, 2,2,2,2, -1,0,1,2};
__device__ __constant__ float PRF_Y[16] = {-2,-1,0,1, 2,2,2,2, -1,0,1,2, -2,-2,-2,-2};

__device__ __forceinline__ unsigned short f2bf(float f) {
    unsigned u = __float_as_uint(f);
    u = (u + 0x7FFF + ((u >> 16) & 1)) >> 16;    // RNE
    return (unsigned short)u;
}
__device__ __forceinline__ float bf2f(unsigned short h) {
    return __uint_as_float(((unsigned)h) << 16);
}

// ---------------- split x -> bf16 hi/lo planes; zero the pad page ----------------
__global__ __launch_bounds__(256) void k_split_x(const float* __restrict__ x,
                                                 unsigned short* __restrict__ XH,
                                                 unsigned short* __restrict__ XL,
                                                 unsigned short* __restrict__ ZP) {
    if (blockIdx.x == 0 && threadIdx.x < 32) ZP[threadIdx.x] = 0;
    int idx = blockIdx.x * 256 + threadIdx.x;          // 4 elems each
    float4 v = *(const float4*)(x + (size_t)idx * 4);
    ushort4 hh, ll;
    float f, fh;
    f = v.x; hh.x = f2bf(f); fh = bf2f(hh.x); ll.x = f2bf(f - fh);
    f = v.y; hh.y = f2bf(f); fh = bf2f(hh.y); ll.y = f2bf(f - fh);
    f = v.z; hh.z = f2bf(f); fh = bf2f(hh.z); ll.z = f2bf(f - fh);
    f = v.w; hh.w = f2bf(f); fh = bf2f(hh.w); ll.w = f2bf(f - fh);
    *(ushort4*)(XH + (size_t)idx * 4) = hh;
    *(ushort4*)(XL + (size_t)idx * 4) = ll;
}

// ---------------- mix-scaled, TRANSPOSED weights WT[n][k], bf16 hi/lo ----------------
__global__ __launch_bounds__(256) void k_wcat_t(const float* __restrict__ Wk,
                                                const float* __restrict__ Wv,
                                                const float* __restrict__ Wr,
                                                const float* __restrict__ mk,
                                                const float* __restrict__ mv,
                                                const float* __restrict__ mr,
                                                unsigned short* __restrict__ WTH,
                                                unsigned short* __restrict__ WTL) {
    int idx = blockIdx.x * 256 + threadIdx.x;          // over 576*384
    int n = idx / 384, k = idx - n * 384;
    int sec = n / CC, nc = n - sec * CC;
    const float* W   = (sec == 0) ? Wk : (sec == 1) ? Wv : Wr;
    const float* mix = (sec == 0) ? mk : (sec == 1) ? mv : mr;
    float wv = (k < CC) ? mix[k] * W[k * CC + nc]
                        : (1.0f - mix[k - CC]) * W[(k - CC) * CC + nc];
    unsigned short h = f2bf(wv);
    WTH[idx] = h;
    WTL[idx] = f2bf(wv - bf2f(h));
}

// ---------------- WoT[n][k] bf16 hi/lo ----------------
__global__ __launch_bounds__(256) void k_prep_wo(const float* __restrict__ Wo,
                                                 unsigned short* __restrict__ WoTH,
                                                 unsigned short* __restrict__ WoTL) {
    int idx = blockIdx.x * 256 + threadIdx.x;          // over 192*192
    int n = idx / CC, k = idx - n * CC;
    float wv = Wo[k * CC + n];
    unsigned short h = f2bf(wv);
    WoTH[idx] = h;
    WoTL[idx] = f2bf(wv - bf2f(h));
}

// ---------------- GEMM1 (MFMA): Z = [x | qshift(x)] @ Wcat, bf16-split ----------------
// M=8192 N=576 K=384. Block 128 thr = 2 waves; tile 128x64; wave 64x64 = 4x4 frags.
// K-step 32, single-buffer LDS, global prefetch issued before MFMA block.
__global__ __launch_bounds__(128, 2) void k_gemm1_mfma(
        const unsigned short* __restrict__ XH, const unsigned short* __restrict__ XL,
        const unsigned short* __restrict__ WTH, const unsigned short* __restrict__ WTL,
        const unsigned short* __restrict__ ZP,
        float* __restrict__ ZTk, float* __restrict__ Zv, float* __restrict__ ZTr) {
    __shared__ unsigned short sAh[128 * 32], sAl[128 * 32];
    __shared__ unsigned short sBh[64 * 32],  sBl[64 * 32];
    const int tid  = threadIdx.x;
    const int w    = tid >> 6;
    const int lane = tid & 63;
    const int bx = blockIdx.x;              // 0..8
    const int bm = blockIdx.y * 128;
    const int bn = bx * 64;

    const int lc  = tid & 3;                // chunk of 8 bf16
    const int ar0 = tid >> 2;               // 0..31

    f32x4 acc[4][4];
#pragma unroll
    for (int i = 0; i < 4; ++i)
#pragma unroll
        for (int j = 0; j < 4; ++j) acc[i][j] = f32x4{0.f, 0.f, 0.f, 0.f};

    uint4 rA[8], rB[4];

    auto loadA = [&](int step) {
        int k0 = step * 32;
#pragma unroll
        for (int q = 0; q < 4; ++q) {
            int rloc = ar0 + q * 32;
            int rg = bm + rloc;
            const unsigned short *srcH, *srcL;
            if (k0 < CC) {
                size_t o = (size_t)rg * CC + k0 + lc * 8;
                srcH = XH + o; srcL = XL + o;
            } else {
                int c = k0 - CC + lc * 8;
                int g = c / 48;
                int t = rg & (TLEN - 1);
                int ri = t >> 6, rj = t & 63;
                int dr; bool ok;
                if      (g == 0) { dr = -1;  ok = (rj > 0);  }
                else if (g == 1) { dr =  1;  ok = (rj < 63); }
                else if (g == 2) { dr = -64; ok = (ri > 0);  }
                else             { dr =  64; ok = (ri < 63); }
                if (ok) { size_t o = (size_t)(rg + dr) * CC + c; srcH = XH + o; srcL = XL + o; }
                else    { srcH = ZP; srcL = ZP; }
            }
            rA[q * 2]     = *(const uint4*)srcH;
            rA[q * 2 + 1] = *(const uint4*)srcL;
        }
    };
    auto loadB = [&](int step) {
        int k0 = step * 32;
#pragma unroll
        for (int q = 0; q < 2; ++q) {
            int col = ar0 + q * 32;
            size_t o = (size_t)(bn + col) * 384 + k0 + lc * 8;
            rB[q * 2]     = *(const uint4*)(WTH + o);
            rB[q * 2 + 1] = *(const uint4*)(WTL + o);
        }
    };
    auto writeS = [&]() {
#pragma unroll
        for (int q = 0; q < 4; ++q) {
            int off = (ar0 + q * 32) * 32 + lc * 8;
            *(uint4*)&sAh[off] = rA[q * 2];
            *(uint4*)&sAl[off] = rA[q * 2 + 1];
        }
#pragma unroll
        for (int q = 0; q < 2; ++q) {
            int off = (ar0 + q * 32) * 32 + lc * 8;
            *(uint4*)&sBh[off] = rB[q * 2];
            *(uint4*)&sBl[off] = rB[q * 2 + 1];
        }
    };

    const int r15 = lane & 15, ksub = lane >> 4;
    const int pc8 = ksub * 8;

    loadA(0); loadB(0);
    for (int step = 0; step < 12; ++step) {
        __syncthreads();                    // prior frag reads complete
        writeS();
        __syncthreads();                    // staged data visible
        if (step < 11) { loadA(step + 1); loadB(step + 1); }   // prefetch under MFMA
        bf16x8 ah[4], al[4], bh[4], bl[4];
#pragma unroll
        for (int f = 0; f < 4; ++f) {
            int ra = (w * 64 + f * 16 + r15) * 32 + pc8;
            ah[f] = *(const bf16x8*)&sAh[ra];
            al[f] = *(const bf16x8*)&sAl[ra];
            int rb = (f * 16 + r15) * 32 + pc8;
            bh[f] = *(const bf16x8*)&sBh[rb];
            bl[f] = *(const bf16x8*)&sBl[rb];
        }
#pragma unroll
        for (int fr = 0; fr < 4; ++fr)
#pragma unroll
            for (int fc = 0; fc < 4; ++fc) {
                acc[fr][fc] = __builtin_amdgcn_mfma_f32_16x16x32_bf16(ah[fr], bh[fc], acc[fr][fc], 0, 0, 0);
                acc[fr][fc] = __builtin_amdgcn_mfma_f32_16x16x32_bf16(ah[fr], bl[fc], acc[fr][fc], 0, 0, 0);
                acc[fr][fc] = __builtin_amdgcn_mfma_f32_16x16x32_bf16(al[fr], bh[fc], acc[fr][fc], 0, 0, 0);
            }
    }

    const int sec   = bx / 3;               // 0=k 1=v 2=r
    const int cbase = (bx - sec * 3) * 64;
#pragma unroll
    for (int fr = 0; fr < 4; ++fr) {
        int row0 = bm + w * 64 + fr * 16 + ksub * 4;
#pragma unroll
        for (int fc = 0; fc < 4; ++fc) {
            int col = cbase + fc * 16 + r15;
            f32x4 v = acc[fr][fc];
            if (sec == 1) {
#pragma unroll
                for (int rg = 0; rg < 4; ++rg)
                    Zv[(size_t)(row0 + rg) * CC + col] = v[rg];
            } else {
                float* D = (sec == 0) ? ZTk : ZTr;
                *(float4*)(D + (size_t)col * 8192 + row0) = make_float4(v[0], v[1], v[2], v[3]);
            }
        }
    }
}

// ---------------- GEMM2 (MFMA): out = P @ Wo, bf16-split ----------------
__global__ __launch_bounds__(128, 2) void k_gemm2_mfma(
        const unsigned short* __restrict__ PH, const unsigned short* __restrict__ PL,
        const unsigned short* __restrict__ WoTH, const unsigned short* __restrict__ WoTL,
        float* __restrict__ out) {
    __shared__ unsigned short sAh[128 * 32], sAl[128 * 32];
    __shared__ unsigned short sBh[64 * 32],  sBl[64 * 32];
    const int tid  = threadIdx.x;
    const int w    = tid >> 6;
    const int lane = tid & 63;
    const int bn = blockIdx.x * 64;
    const int bm = blockIdx.y * 128;
    const int lc  = tid & 3;
    const int ar0 = tid >> 2;

    f32x4 acc[4][4];
#pragma unroll
    for (int i = 0; i < 4; ++i)
#pragma unroll
        for (int j = 0; j < 4; ++j) acc[i][j] = f32x4{0.f, 0.f, 0.f, 0.f};

    uint4 rA[8], rB[4];
    auto loadAB = [&](int step) {
        int k0 = step * 32;
#pragma unroll
        for (int q = 0; q < 4; ++q) {
            size_t o = (size_t)(bm + ar0 + q * 32) * CC + k0 + lc * 8;
            rA[q * 2]     = *(const uint4*)(PH + o);
            rA[q * 2 + 1] = *(const uint4*)(PL + o);
        }
#pragma unroll
        for (int q = 0; q < 2; ++q) {
            size_t o = (size_t)(bn + ar0 + q * 32) * CC + k0 + lc * 8;
            rB[q * 2]     = *(const uint4*)(WoTH + o);
            rB[q * 2 + 1] = *(const uint4*)(WoTL + o);
        }
    };
    auto writeS = [&]() {
#pragma unroll
        for (int q = 0; q < 4; ++q) {
            int off = (ar0 + q * 32) * 32 + lc * 8;
            *(uint4*)&sAh[off] = rA[q * 2];
            *(uint4*)&sAl[off] = rA[q * 2 + 1];
        }
#pragma unroll
        for (int q = 0; q < 2; ++q) {
            int off = (ar0 + q * 32) * 32 + lc * 8;
            *(uint4*)&sBh[off] = rB[q * 2];
            *(uint4*)&sBl[off] = rB[q * 2 + 1];
        }
    };

    const int r15 = lane & 15, ksub = lane >> 4;
    const int pc8 = ksub * 8;

    loadAB(0);
    for (int step = 0; step < 6; ++step) {
        __syncthreads();
        writeS();
        __syncthreads();
        if (step < 5) loadAB(step + 1);
        bf16x8 ah[4], al[4], bh[4], bl[4];
#pragma unroll
        for (int f = 0; f < 4; ++f) {
            int ra = (w * 64 + f * 16 + r15) * 32 + pc8;
            ah[f] = *(const bf16x8*)&sAh[ra];
            al[f] = *(const bf16x8*)&sAl[ra];
            int rb = (f * 16 + r15) * 32 + pc8;
            bh[f] = *(const bf16x8*)&sBh[rb];
            bl[f] = *(const bf16x8*)&sBl[rb];
        }
#pragma unroll
        for (int fr = 0; fr < 4; ++fr)
#pragma unroll
            for (int fc = 0; fc < 4; ++fc) {
                acc[fr][fc] = __builtin_amdgcn_mfma_f32_16x16x32_bf16(ah[fr], bh[fc], acc[fr][fc], 0, 0, 0);
                acc[fr][fc] = __builtin_amdgcn_mfma_f32_16x16x32_bf16(ah[fr], bl[fc], acc[fr][fc], 0, 0, 0);
                acc[fr][fc] = __builtin_amdgcn_mfma_f32_16x16x32_bf16(al[fr], bh[fc], acc[fr][fc], 0, 0, 0);
            }
    }

#pragma unroll
    for (int fr = 0; fr < 4; ++fr) {
        int row0 = bm + w * 64 + fr * 16 + ksub * 4;
#pragma unroll
        for (int fc = 0; fc < 4; ++fc) {
            int col = bn + fc * 16 + r15;
            f32x4 v = acc[fr][fc];
#pragma unroll
            for (int rg = 0; rg < 4; ++rg)
                out[(size_t)(row0 + rg) * CC + col] = v[rg];
        }
    }
}

// ---------------- fused band_est + ada_peak (RMW into pixel-major Zv) -------
__global__ __launch_bounds__(192) void k_bandpeak(const float* __restrict__ x,
                                                  const float* __restrict__ cvw,
                                                  const float* __restrict__ cvb,
                                                  const float* __restrict__ bns_v,
                                                  const float* __restrict__ bnb_v,
                                                  const float* __restrict__ chw,
                                                  const float* __restrict__ chb,
                                                  const float* __restrict__ bns_h,
                                                  const float* __restrict__ bnb_h,
                                                  float* __restrict__ Zv) {
    int pixg = blockIdx.x;
    int b   = pixg >> 12;
    int pix = pixg & 4095;
    int i = pix >> 6, j = pix & 63;
    int c = threadIdx.x;
    size_t xbase = (size_t)b * TLEN * CC;

    float sv0 = 0.f, sv1 = 0.f, sh0 = 0.f, sh1 = 0.f;
#pragma unroll
    for (int t = 0; t < 7; ++t) {
        int ii = i + t - 3;
        if (ii >= 0 && ii < 64) {
            float xv = x[xbase + (size_t)(ii * 64 + j) * CC + c];
            sv0 = fmaf(xv, cvw[(0 * CC + c) * 7 + t], sv0);
            sv1 = fmaf(xv, cvw[(1 * CC + c) * 7 + t], sv1);
        }
        int jj = j + t - 3;
        if (jj >= 0 && jj < 64) {
            float xh = x[xbase + (size_t)(i * 64 + jj) * CC + c];
            sh0 = fmaf(xh, chw[(0 * CC + c) * 7 + t], sh0);
            sh1 = fmaf(xh, chw[(1 * CC + c) * 7 + t], sh1);
        }
    }
    __shared__ float red[4][CC];
    __shared__ float gsh[4];
    red[0][c] = sv0; red[1][c] = sv1; red[2][c] = sh0; red[3][c] = sh1;
    __syncthreads();
    if (c < 64) {
#pragma unroll
        for (int r = 0; r < 4; ++r) {
            float v = red[r][c] + red[r][c + 64] + red[r][c + 128];
            v += __shfl_xor(v, 32);
            v += __shfl_xor(v, 16);
            v += __shfl_xor(v, 8);
            v += __shfl_xor(v, 4);
            v += __shfl_xor(v, 2);
            v += __shfl_xor(v, 1);
            if (c == 0) {
                const float inv = 0.9999950000374997f;    // 1/sqrt(1+1e-5)
                float bias, sc, sh;
                if (r < 2) { bias = cvb[r];     sc = bns_v[r];     sh = bnb_v[r]; }
                else       { bias = chb[r - 2]; sc = bns_h[r - 2]; sh = bnb_h[r - 2]; }
                float g = (v + bias) * (sc * inv) + sh;
                gsh[r] = 2.0f / (1.0f + expf(-g));        // sigmoid * (GB_MAX-1)
            }
        }
    }
    __syncthreads();

    __shared__ int   l_lt[16], l_rb[16];
    __shared__ float l_glt[16], l_grb[16];
    if (c < 16) {
        int n = c, blk = n >> 2;
        float mx = (blk == 0) ? -gsh[0] : (blk == 2) ? gsh[1] : 0.0f;
        float my = (blk == 1) ?  gsh[3] : (blk == 3) ? -gsh[2] : 0.0f;
        float px = (float)(i + PADC) + PRF_X[n] + mx;
        float py = (float)(j + PADC) + PRF_Y[n] + my;
        float flx = floorf(px), fly = floorf(py);
        float qltx = fminf(fmaxf(flx, 0.f), 67.f);
        float qlty = fminf(fmaxf(fly, 0.f), 67.f);
        float qrbx = fminf(fmaxf(flx + 1.f, 0.f), 67.f);
        float qrby = fminf(fmaxf(fly + 1.f, 0.f), 67.f);
        float pxc = fminf(fmaxf(px, 0.f), 67.f);
        float pyc = fminf(fmaxf(py, 0.f), 67.f);
        float glt = (1.f + (qltx - pxc)) * (1.f + (qlty - pyc));
        float grb = (1.f - (qrbx - pxc)) * (1.f - (qrby - pyc));
        int sltx = min(max((int)qltx - PADC, 0), 63);
        int slty = min(max((int)qlty - PADC, 0), 63);
        int srbx = min(max((int)qrbx - PADC, 0), 63);
        int srby = min(max((int)qrby - PADC, 0), 63);
        l_lt[n] = sltx * 64 + slty;
        l_rb[n] = srbx * 64 + srby;
        l_glt[n] = glt;
        l_grb[n] = grb;
    }
    __syncthreads();

    float acc = 0.f;
#pragma unroll
    for (int n = 0; n < 16; ++n) {
        acc = fmaf(l_glt[n], x[xbase + (size_t)l_lt[n] * CC + c], acc);
        acc = fmaf(l_grb[n], x[xbase + (size_t)l_rb[n] * CC + c], acc);
    }
    float peak = x[xbase + (size_t)pix * CC + c] - acc * 0.0625f;
    Zv[((size_t)b * TLEN + pix) * CC + c] += peak;
}

// ---------------- transpose v: Zv[8192][192] -> ZTv[192][8192] ----------------
__global__ __launch_bounds__(256) void k_transv(const float* __restrict__ Zv,
                                                float* __restrict__ ZTv) {
    __shared__ float tile[64][65];
    int tid = threadIdx.x;
    int rb = (blockIdx.x & 127) * 64;
    int cb = (blockIdx.x >> 7) * 64;
    int tr  = tid >> 4;
    int tc4 = (tid & 15) * 4;
#pragma unroll
    for (int q = 0; q < 4; ++q) {
        int r = tr + q * 16;
        float4 v = *(const float4*)(Zv + (size_t)(rb + r) * CC + cb + tc4);
        *(float4*)&tile[r][tc4] = v;
    }
    __syncthreads();
#pragma unroll
    for (int q = 0; q < 4; ++q) {
        int ccol = tr + q * 16;
        float4 o = {tile[tc4 + 0][ccol], tile[tc4 + 1][ccol],
                    tile[tc4 + 2][ccol], tile[tc4 + 3][ccol]};
        *(float4*)(ZTv + (size_t)(cb + ccol) * 8192 + rb + tc4) = o;
    }
}

// ---------------- transpose+split P: PT[192][8192] f32 -> PH/PL[8192][192] bf16 ----
__global__ __launch_bounds__(256) void k_transP(const float* __restrict__ PT,
                                                unsigned short* __restrict__ PH,
                                                unsigned short* __restrict__ PL) {
    __shared__ float tile[64][65];
    int tid = threadIdx.x;
    int mb = (blockIdx.x & 127) * 64;     // over 8192
    int cb = (blockIdx.x >> 7) * 64;      // over 192
    int tr  = tid >> 4;
    int tc4 = (tid & 15) * 4;
#pragma unroll
    for (int q = 0; q < 4; ++q) {
        int cr = tr + q * 16;
        float4 v = *(const float4*)(PT + (size_t)(cb + cr) * 8192 + mb + tc4);
        *(float4*)&tile[cr][tc4] = v;
    }
    __syncthreads();
#pragma unroll
    for (int q = 0; q < 4; ++q) {
        int m = tr + q * 16;
        ushort4 hh, ll;
        float f, fh;
        f = tile[tc4 + 0][m]; hh.x = f2bf(f); fh = bf2f(hh.x); ll.x = f2bf(f - fh);
        f = tile[tc4 + 1][m]; hh.y = f2bf(f); fh = bf2f(hh.y); ll.y = f2bf(f - fh);
        f = tile[tc4 + 2][m]; hh.z = f2bf(f); fh = bf2f(hh.z); ll.z = f2bf(f - fh);
        f = tile[tc4 + 3][m]; hh.w = f2bf(f); fh = bf2f(hh.w); ll.w = f2bf(f - fh);
        size_t o = (size_t)(mb + m) * CC + cb + tc4;
        *(ushort4*)(PH + o) = hh;
        *(ushort4*)(PL + o) = ll;
    }
}

// ---------------- bi_wkv: chunked associative scan, coalesced ZT loads -------
__global__ __launch_bounds__(256) void k_wkv2(const float* __restrict__ ZT,
                                              float* __restrict__ PT,
                                              const float* __restrict__ sd,
                                              const float* __restrict__ sf) {
    const int NTH = 256, CH = 16;
    int c = blockIdx.x % CC;
    int b = blockIdx.x / CC;
    const float w = sd[c] * (1.0f / 4096.0f);
    const float u = sf[c] * (1.0f / 4096.0f);

    __shared__ float s_m[NTH], s_a[NTH], s_b[NTH], s_L[NTH];

    int tid = threadIdx.x;
    int s = tid * CH;
    size_t rowbase = (size_t)b * TLEN;

    float kr[CH], vr[CH], rr[CH];
    {
        const float* pk = ZT + (size_t)c * 8192 + rowbase + s;
        const float* pv = ZT + (size_t)(CC + c) * 8192 + rowbase + s;
        const float* pr = ZT + (size_t)(2 * CC + c) * 8192 + rowbase + s;
#pragma unroll
        for (int q = 0; q < 4; ++q) {
            *(float4*)&kr[q * 4] = *(const float4*)(pk + q * 4);
            *(float4*)&vr[q * 4] = *(const float4*)(pv + q * 4);
            *(float4*)&rr[q * 4] = *(const float4*)(pr + q * 4);
        }
    }

    float m = -1e38f, a = 0.f, bb = 0.f;
#pragma unroll
    for (int jj = 0; jj < CH; ++jj) {
        float kt = kr[jj], vt = vr[jj];
        float m2 = fmaxf(m - w, kt);
        float e1 = expf(m - w - m2);
        float e2 = expf(kt - m2);
        a = e1 * a + e2;
        bb = e1 * bb + e2 * vt;
        m = m2;
    }
    s_m[tid] = m; s_a[tid] = a; s_b[tid] = bb; s_L[tid] = (float)CH;
    float L = (float)CH;
    for (int d = 1; d < NTH; d <<= 1) {
        __syncthreads();
        float pm = 0, pa = 0, pb = 0, pL = 0;
        bool has = (tid >= d);
        if (has) { pm = s_m[tid - d]; pa = s_a[tid - d]; pb = s_b[tid - d]; pL = s_L[tid - d]; }
        __syncthreads();
        if (has) {
            float pdec = pm - L * w;
            float m2 = fmaxf(pdec, m);
            float e1 = expf(pdec - m2);
            float e2 = expf(m - m2);
            a  = e1 * pa + e2 * a;
            bb = e1 * pb + e2 * bb;
            m = m2; L += pL;
            s_m[tid] = m; s_a[tid] = a; s_b[tid] = bb; s_L[tid] = L;
        }
    }
    __syncthreads();
    float fm = -1e38f, fa = 0.f, fb = 0.f;
    if (tid > 0) { fm = s_m[tid - 1]; fa = s_a[tid - 1]; fb = s_b[tid - 1]; }
    __syncthreads();

    m = -1e38f; a = 0.f; bb = 0.f;
#pragma unroll
    for (int jj = CH - 1; jj >= 0; --jj) {
        float kt = kr[jj], vt = vr[jj];
        float m2 = fmaxf(m - w, kt);
        float e1 = expf(m - w - m2);
        float e2 = expf(kt - m2);
        a = e1 * a + e2;
        bb = e1 * bb + e2 * vt;
        m = m2;
    }
    s_m[tid] = m; s_a[tid] = a; s_b[tid] = bb; s_L[tid] = (float)CH;
    L = (float)CH;
    for (int d = 1; d < NTH; d <<= 1) {
        __syncthreads();
        float pm = 0, pa = 0, pb = 0, pL = 0;
        bool has = (tid + d) < NTH;
        if (has) { pm = s_m[tid + d]; pa = s_a[tid + d]; pb = s_b[tid + d]; pL = s_L[tid + d]; }
        __syncthreads();
        if (has) {
            float pdec = pm - L * w;
            float m2 = fmaxf(m, pdec);
            float e1 = expf(m - m2);
            float e2 = expf(pdec - m2);
            a  = e1 * a + e2 * pa;
            bb = e1 * bb + e2 * pb;
            m = m2; L += pL;
            s_m[tid] = m; s_a[tid] = a; s_b[tid] = bb; s_L[tid] = L;
        }
    }
    __syncthreads();
    float bm = -1e38f, ba = 0.f, bbv = 0.f;
    if (tid < NTH - 1) { bm = s_m[tid + 1]; ba = s_a[tid + 1]; bbv = s_b[tid + 1]; }

    float em[CH], ea[CH], eb[CH];
    m = bm; a = ba; bb = bbv;
#pragma unroll
    for (int jj = CH - 1; jj >= 0; --jj) {
        em[jj] = m; ea[jj] = a; eb[jj] = bb;
        float kt = kr[jj], vt = vr[jj];
        float m2 = fmaxf(m - w, kt);
        float e1 = expf(m - w - m2);
        float e2 = expf(kt - m2);
        a = e1 * a + e2;
        bb = e1 * bb + e2 * vt;
        m = m2;
    }

    m = fm; a = fa; bb = fb;
#pragma unroll
    for (int jj = 0; jj < CH; ++jj) {
        float kt = kr[jj], vt = vr[jj];
        float ms = u + kt;
        float M = fmaxf(fmaxf(m, em[jj]), ms);
        float ef  = expf(m - M);
        float ebk = expf(em[jj] - M);
        float es  = expf(ms - M);
        float num = ef * bb + ebk * eb[jj] + es * vt;
        float den = ef * a + ebk * ea[jj] + es;
        float y = num / den;
        float sr = 1.0f / (1.0f + expf(-rr[jj]));
        PT[(size_t)c * 8192 + rowbase + s + jj] = sr * y;
        float m2 = fmaxf(m - w, kt);
        float e1 = expf(m - w - m2);
        float e2 = expf(kt - m2);
        a = e1 * a + e2;
        bb = e1 * bb + e2 * vt;
        m = m2;
    }
}

extern "C" void kernel_launch(void* const* d_in, const int* in_sizes, int n_in,
                              void* d_out, int out_size, void* d_ws, size_t ws_size,
                              hipStream_t stream) {
    const float* x     = (const float*)d_in[0];
    const float* mix_k = (const float*)d_in[3];
    const float* mix_v = (const float*)d_in[4];
    const float* mix_r = (const float*)d_in[5];
    const float* Wk    = (const float*)d_in[6];
    const float* Wv    = (const float*)d_in[7];
    const float* Wr    = (const float*)d_in[8];
    const float* Wo    = (const float*)d_in[9];
    const float* sd    = (const float*)d_in[10];
    const float* sf    = (const float*)d_in[11];
    const float* cvw   = (const float*)d_in[12];
    const float* cvb   = (const float*)d_in[13];
    const float* bns_v = (const float*)d_in[14];
    const float* bnb_v = (const float*)d_in[15];
    const float* chw   = (const float*)d_in[16];
    const float* chb   = (const float*)d_in[17];
    const float* bns_h = (const float*)d_in[18];
    const float* bnb_h = (const float*)d_in[19];
    float* out = (float*)d_out;
    char* W = (char*)d_ws;

    // byte-offset workspace plan (26.2 MB total; 32.4 MB proven available):
    float*          Zv   = (float*)(W + 0);            // [8192][192] f32 (later PT)
    float*          ZTk  = (float*)(W + 6291456);      // ZT base (k|v|r planes contiguous)
    float*          ZTv  = (float*)(W + 12582912);
    float*          ZTr  = (float*)(W + 18874368);
    unsigned short* XH   = (unsigned short*)(W + 12582912);  // overlays ZTv until transv
    unsigned short* XL   = (unsigned short*)(W + 15728640);
    unsigned short* PH   = (unsigned short*)(W + 6291456);   // overlays ZTk after wkv2
    unsigned short* PL   = (unsigned short*)(W + 9437184);
    float*          PT   = Zv;                                // Zv dead after transv
    unsigned short* WTH  = (unsigned short*)(W + 25165824);
    unsigned short* WTL  = (unsigned short*)(W + 25608192);
    unsigned short* WoTH = (unsigned short*)(W + 26050560);
    unsigned short* WoTL = (unsigned short*)(W + 26124288);
    unsigned short* ZP   = (unsigned short*)(W + 26198016);

    k_split_x<<<1536, 256, 0, stream>>>(x, XH, XL, ZP);
    k_wcat_t<<<864, 256, 0, stream>>>(Wk, Wv, Wr, mix_k, mix_v, mix_r, WTH, WTL);
    k_prep_wo<<<144, 256, 0, stream>>>(Wo, WoTH, WoTL);
    k_gemm1_mfma<<<dim3(9, 64), 128, 0, stream>>>(XH, XL, WTH, WTL, ZP, ZTk, Zv, ZTr);
    k_bandpeak<<<8192, 192, 0, stream>>>(x, cvw, cvb, bns_v, bnb_v, chw, chb, bns_h, bnb_h, Zv);
    k_transv<<<384, 256, 0, stream>>>(Zv, ZTv);
    k_wkv2<<<384, 256, 0, stream>>>(ZTk, PT, sd, sf);
    k_transP<<<384, 256, 0, stream>>>(PT, PH, PL);
    k_gemm2_mfma<<<dim3(3, 64), 128, 0, stream>>>(PH, PL, WoTH, WoTL, out);
}